// Round 1
// baseline (676.786 us; speedup 1.0000x reference)
//
#include <hip/hip_runtime.h>

constexpr int N_ = 100000;
constexpr int E_ = 1600000;
constexpr int FIN = 128;
constexpr int FH  = 64;
constexpr int FC  = 40;
constexpr int NB_SCAN = (N_ + 255) / 256;   // 391

// ---------------- degree / norm ----------------

__global__ __launch_bounds__(256) void k_init(float* deg, int* cnt, int* fill) {
  int i = blockIdx.x * 256 + threadIdx.x;
  if (i < N_) { deg[i] = 1.0f; cnt[i] = 0; fill[i] = 0; }  // self-loop weight 1
}

__global__ __launch_bounds__(256) void k_edge_deg(const int* __restrict__ ei,
                                                  const float* __restrict__ ew,
                                                  float* deg, int* cnt) {
  int e = blockIdx.x * 256 + threadIdx.x;
  if (e >= E_) return;
  int d = ei[E_ + e];                 // dst = edge_index[1]
  atomicAdd(&deg[d], ew[e]);
  atomicAdd(&cnt[d], 1);
}

__global__ __launch_bounds__(256) void k_dinv(float* deg) {
  int i = blockIdx.x * 256 + threadIdx.x;
  if (i < N_) {
    float dg = deg[i];
    deg[i] = dg > 0.f ? rsqrtf(fmaxf(dg, 1e-30f)) : 0.f;   // becomes dinv
  }
}

// ---------------- exclusive scan (rowptr) ----------------

__global__ __launch_bounds__(256) void k_scan1(const int* __restrict__ cnt,
                                               int* __restrict__ partial,
                                               int* __restrict__ bsums) {
  __shared__ int s[256];
  int t = threadIdx.x, gid = blockIdx.x * 256 + t;
  int v = (gid < N_) ? cnt[gid] : 0;
  s[t] = v; __syncthreads();
  for (int off = 1; off < 256; off <<= 1) {
    int u = (t >= off) ? s[t - off] : 0;
    __syncthreads();
    s[t] += u; __syncthreads();
  }
  if (gid < N_) partial[gid] = s[t] - v;          // exclusive within block
  if (t == 255) bsums[blockIdx.x] = s[255];       // block total
}

__global__ __launch_bounds__(512) void k_scan2(int* bsums) {
  __shared__ int s[512];
  int t = threadIdx.x;
  int v = (t < NB_SCAN) ? bsums[t] : 0;
  s[t] = v; __syncthreads();
  for (int off = 1; off < 512; off <<= 1) {
    int u = (t >= off) ? s[t - off] : 0;
    __syncthreads();
    s[t] += u; __syncthreads();
  }
  if (t < NB_SCAN) bsums[t] = s[t] - v;           // exclusive
  if (t == 511) bsums[NB_SCAN] = s[511];          // grand total (== E_)
}

__global__ __launch_bounds__(256) void k_scan3(const int* __restrict__ partial,
                                               const int* __restrict__ bsums,
                                               int* __restrict__ rowptr) {
  int gid = blockIdx.x * 256 + threadIdx.x;
  if (gid < N_)       rowptr[gid] = partial[gid] + bsums[gid >> 8];
  else if (gid == N_) rowptr[N_]  = bsums[NB_SCAN];
}

// ---------------- CSR fill ----------------

__global__ __launch_bounds__(256) void k_fill(const int* __restrict__ ei,
                                              const float* __restrict__ ew,
                                              const float* __restrict__ dinv,
                                              const int* __restrict__ rowptr,
                                              int* fill,
                                              int* __restrict__ csr_src,
                                              float* __restrict__ csr_norm) {
  int e = blockIdx.x * 256 + threadIdx.x;
  if (e >= E_) return;
  int s = ei[e], d = ei[E_ + e];
  float nm = dinv[s] * ew[e] * dinv[d];
  int pos = rowptr[d] + atomicAdd(&fill[d], 1);
  csr_src[pos]  = s;
  csr_norm[pos] = nm;
}

// ---------------- GEMM1: h1 = x @ W1  (128 -> 64) ----------------

__global__ __launch_bounds__(256) void k_gemm1(const float* __restrict__ x,
                                               const float* __restrict__ W1,
                                               float* __restrict__ h1) {
  __shared__ float Ws[FIN * FH];   // 32 KB, layout [k][c]
  __shared__ float xs[8 * FIN];    // 4 KB
  int t = threadIdx.x;
  int base = blockIdx.x * 8;
  for (int i = t; i < FIN * FH; i += 256) Ws[i] = W1[i];
  for (int i = t; i < 8 * FIN; i += 256) {
    int r = i >> 7, k = i & 127;
    xs[i] = (base + r < N_) ? x[(size_t)(base + r) * FIN + k] : 0.f;
  }
  __syncthreads();
  int c = t & 63, r0 = t >> 6;        // wave id = row group, lane = output col
  float a0 = 0.f, a1 = 0.f;
  #pragma unroll 4
  for (int k = 0; k < FIN; ++k) {
    float wv = Ws[k * FH + c];        // lanes span 64 cols -> 2-way (free)
    a0 += xs[r0 * FIN + k] * wv;      // broadcast
    a1 += xs[(r0 + 4) * FIN + k] * wv;
  }
  if (base + r0 < N_)     h1[(size_t)(base + r0) * FH + c] = a0;
  if (base + r0 + 4 < N_) h1[(size_t)(base + r0 + 4) * FH + c] = a1;
}

// ---------------- aggregate 1 + bias + relu ----------------

__global__ __launch_bounds__(256) void k_agg1(const float* __restrict__ h1,
                                              const float* __restrict__ dinv,
                                              const int* __restrict__ rowptr,
                                              const int* __restrict__ csr_src,
                                              const float* __restrict__ csr_norm,
                                              const float* __restrict__ b1,
                                              float* __restrict__ h1r) {
  int wave = threadIdx.x >> 6, lane = threadIdx.x & 63;
  int i = blockIdx.x * 4 + wave;
  if (i >= N_) return;
  float di = dinv[i];
  float acc = di * di * h1[(size_t)i * FH + lane];   // self-loop
  int e0 = rowptr[i], e1 = rowptr[i + 1];
  for (int e = e0; e < e1; ++e) {
    int s = csr_src[e];
    float nm = csr_norm[e];
    acc += nm * h1[(size_t)s * FH + lane];           // coalesced 256B gather
  }
  acc += b1[lane];
  h1r[(size_t)i * FH + lane] = fmaxf(acc, 0.f);
}

// ---------------- GEMM2: h2 = h1r @ W2  (64 -> 40) ----------------

__global__ __launch_bounds__(256) void k_gemm2(const float* __restrict__ h1r,
                                               const float* __restrict__ W2,
                                               float* __restrict__ h2) {
  __shared__ float Ws[FH * FC];   // 10 KB, layout [k][c]
  int t = threadIdx.x;
  for (int i = t; i < FH * FC; i += 256) Ws[i] = W2[i];
  __syncthreads();
  int wave = t >> 6, lane = t & 63;
  int row = blockIdx.x * 4 + wave;
  if (row >= N_) return;
  if (lane < FC) {
    const float* hr = h1r + (size_t)row * FH;
    float acc = 0.f;
    #pragma unroll 8
    for (int k = 0; k < FH; ++k) acc += hr[k] * Ws[k * FC + lane];  // hr[k] broadcast
    h2[(size_t)row * FC + lane] = acc;
  }
}

// ---------------- aggregate 2 + bias + L2 normalize ----------------

__global__ __launch_bounds__(256) void k_agg2(const float* __restrict__ h2,
                                              const float* __restrict__ dinv,
                                              const int* __restrict__ rowptr,
                                              const int* __restrict__ csr_src,
                                              const float* __restrict__ csr_norm,
                                              const float* __restrict__ b2,
                                              float* __restrict__ out) {
  int wave = threadIdx.x >> 6, lane = threadIdx.x & 63;
  int i = blockIdx.x * 4 + wave;
  if (i >= N_) return;
  float di = dinv[i];
  int e0 = rowptr[i], e1 = rowptr[i + 1];
  float acc = 0.f;
  if (lane < FC) acc = di * di * h2[(size_t)i * FC + lane];
  for (int e = e0; e < e1; ++e) {
    int s = csr_src[e];
    float nm = csr_norm[e];
    if (lane < FC) acc += nm * h2[(size_t)s * FC + lane];
  }
  if (lane < FC) acc += b2[lane];
  float sq = (lane < FC) ? acc * acc : 0.f;
  for (int off = 32; off > 0; off >>= 1) sq += __shfl_xor(sq, off, 64);
  float nrm = sqrtf(sq);
  if (lane < FC) out[(size_t)i * FC + lane] = acc / fmaxf(nrm, 1e-12f);
}

// ---------------- launch ----------------

extern "C" void kernel_launch(void* const* d_in, const int* in_sizes, int n_in,
                              void* d_out, int out_size, void* d_ws, size_t ws_size,
                              hipStream_t stream) {
  const float* x  = (const float*)d_in[0];
  const int*   ei = (const int*)d_in[1];
  const float* ew = (const float*)d_in[2];
  const float* W1 = (const float*)d_in[3];
  const float* b1 = (const float*)d_in[4];
  const float* W2 = (const float*)d_in[5];
  const float* b2 = (const float*)d_in[6];
  float* out = (float*)d_out;

  char* ws = (char*)d_ws;
  size_t off = 0;
  auto alloc = [&](size_t bytes) -> char* {
    char* p = ws + off;
    off = (off + bytes + 255) & ~(size_t)255;
    return p;
  };
  float* deg     = (float*)alloc((size_t)N_ * 4);      // becomes dinv after k_dinv
  int*   cnt     = (int*)  alloc((size_t)N_ * 4);
  int*   fill    = (int*)  alloc((size_t)N_ * 4);
  int*   partial = (int*)  alloc((size_t)N_ * 4);
  int*   bsums   = (int*)  alloc((size_t)(NB_SCAN + 1) * 4);
  int*   rowptr  = (int*)  alloc((size_t)(N_ + 1) * 4);
  int*   csr_src = (int*)  alloc((size_t)E_ * 4);
  float* csr_nrm = (float*)alloc((size_t)E_ * 4);
  float* h1      = (float*)alloc((size_t)N_ * FH * 4);
  float* h1r     = (float*)alloc((size_t)N_ * FH * 4);
  float* h2      = (float*)alloc((size_t)N_ * FC * 4);
  (void)ws_size; (void)in_sizes; (void)n_in; (void)out_size;

  k_init    <<<(N_ + 255) / 256, 256, 0, stream>>>(deg, cnt, fill);
  k_edge_deg<<<(E_ + 255) / 256, 256, 0, stream>>>(ei, ew, deg, cnt);
  k_dinv    <<<(N_ + 255) / 256, 256, 0, stream>>>(deg);
  k_scan1   <<<NB_SCAN,          256, 0, stream>>>(cnt, partial, bsums);
  k_scan2   <<<1,                512, 0, stream>>>(bsums);
  k_scan3   <<<(N_ + 1 + 255) / 256, 256, 0, stream>>>(partial, bsums, rowptr);
  k_fill    <<<(E_ + 255) / 256, 256, 0, stream>>>(ei, ew, deg, rowptr, fill, csr_src, csr_nrm);
  k_gemm1   <<<(N_ + 7) / 8,     256, 0, stream>>>(x, W1, h1);
  k_agg1    <<<(N_ + 3) / 4,     256, 0, stream>>>(h1, deg, rowptr, csr_src, csr_nrm, b1, h1r);
  k_gemm2   <<<(N_ + 3) / 4,     256, 0, stream>>>(h1r, W2, h2);
  k_agg2    <<<(N_ + 3) / 4,     256, 0, stream>>>(h2, deg, rowptr, csr_src, csr_nrm, b2, out);
}

// Round 2
// 505.216 us; speedup vs baseline: 1.3396x; 1.3396x over previous
//
#include <hip/hip_runtime.h>

constexpr int N_ = 100000;
constexpr int E_ = 1600000;
constexpr int FIN = 128;
constexpr int FH  = 64;
constexpr int FC  = 40;
constexpr int NB_SCAN = (N_ + 255) / 256;   // 391
constexpr int G1_ROWS = 32;

// ---------------- degree / norm ----------------

__global__ __launch_bounds__(256) void k_init(float* deg, int* cnt, int* fill) {
  int i = blockIdx.x * 256 + threadIdx.x;
  if (i < N_) { deg[i] = 1.0f; cnt[i] = 0; fill[i] = 0; }  // self-loop weight 1
}

__global__ __launch_bounds__(256) void k_edge_deg(const int* __restrict__ ei,
                                                  const float* __restrict__ ew,
                                                  float* deg, int* cnt) {
  int e = blockIdx.x * 256 + threadIdx.x;
  if (e >= E_) return;
  int d = ei[E_ + e];                 // dst = edge_index[1]
  atomicAdd(&deg[d], ew[e]);
  atomicAdd(&cnt[d], 1);
}

__global__ __launch_bounds__(256) void k_dinv(float* deg) {
  int i = blockIdx.x * 256 + threadIdx.x;
  if (i < N_) {
    float dg = deg[i];
    deg[i] = dg > 0.f ? rsqrtf(fmaxf(dg, 1e-30f)) : 0.f;   // becomes dinv
  }
}

// ---------------- exclusive scan (rowptr) ----------------

__global__ __launch_bounds__(256) void k_scan1(const int* __restrict__ cnt,
                                               int* __restrict__ partial,
                                               int* __restrict__ bsums) {
  __shared__ int s[256];
  int t = threadIdx.x, gid = blockIdx.x * 256 + t;
  int v = (gid < N_) ? cnt[gid] : 0;
  s[t] = v; __syncthreads();
  for (int off = 1; off < 256; off <<= 1) {
    int u = (t >= off) ? s[t - off] : 0;
    __syncthreads();
    s[t] += u; __syncthreads();
  }
  if (gid < N_) partial[gid] = s[t] - v;          // exclusive within block
  if (t == 255) bsums[blockIdx.x] = s[255];       // block total
}

__global__ __launch_bounds__(512) void k_scan2(int* bsums) {
  __shared__ int s[512];
  int t = threadIdx.x;
  int v = (t < NB_SCAN) ? bsums[t] : 0;
  s[t] = v; __syncthreads();
  for (int off = 1; off < 512; off <<= 1) {
    int u = (t >= off) ? s[t - off] : 0;
    __syncthreads();
    s[t] += u; __syncthreads();
  }
  if (t < NB_SCAN) bsums[t] = s[t] - v;           // exclusive
  if (t == 511) bsums[NB_SCAN] = s[511];          // grand total (== E_)
}

__global__ __launch_bounds__(256) void k_scan3(const int* __restrict__ partial,
                                               const int* __restrict__ bsums,
                                               int* __restrict__ rowptr) {
  int gid = blockIdx.x * 256 + threadIdx.x;
  if (gid < N_)       rowptr[gid] = partial[gid] + bsums[gid >> 8];
  else if (gid == N_) rowptr[N_]  = bsums[NB_SCAN];
}

// ---------------- CSR fill ----------------

__global__ __launch_bounds__(256) void k_fill(const int* __restrict__ ei,
                                              const float* __restrict__ ew,
                                              const float* __restrict__ dinv,
                                              const int* __restrict__ rowptr,
                                              int* fill,
                                              int* __restrict__ csr_src,
                                              float* __restrict__ csr_norm) {
  int e = blockIdx.x * 256 + threadIdx.x;
  if (e >= E_) return;
  int s = ei[e], d = ei[E_ + e];
  float nm = dinv[s] * ew[e] * dinv[d];
  int pos = rowptr[d] + atomicAdd(&fill[d], 1);
  csr_src[pos]  = s;
  csr_norm[pos] = nm;
}

// ---------------- GEMM1: h1 = x @ W1  (128 -> 64) ----------------
// 32 rows/block; thread = (rg 0..15, cg 0..15): 2 rows x 4 cols, float4 LDS.

__global__ __launch_bounds__(256) void k_gemm1(const float* __restrict__ x,
                                               const float* __restrict__ W1,
                                               float* __restrict__ h1) {
  __shared__ float4 Ws4[FIN * 16];      // [k][cg], 32 KB
  __shared__ float4 xs4[G1_ROWS * 32];  // [r][k4], 16 KB
  int t = threadIdx.x;
  const float4* W14 = (const float4*)W1;
  const float4* x4  = (const float4*)x;
  int base = blockIdx.x * G1_ROWS;
  #pragma unroll
  for (int i = 0; i < 8; ++i) Ws4[t + 256 * i] = W14[t + 256 * i];
  #pragma unroll
  for (int i = 0; i < 4; ++i) xs4[t + 256 * i] = x4[(size_t)base * 32 + t + 256 * i];
  __syncthreads();
  int cg = t & 15, rg = t >> 4;
  int r0 = rg * 2, r1 = r0 + 1;
  float4 a0{0, 0, 0, 0}, a1{0, 0, 0, 0};
  #pragma unroll 2
  for (int k4 = 0; k4 < 32; ++k4) {
    float4 xa = xs4[r0 * 32 + k4];
    float4 xb = xs4[r1 * 32 + k4];
    float4 w0 = Ws4[(k4 * 4 + 0) * 16 + cg];
    float4 w1 = Ws4[(k4 * 4 + 1) * 16 + cg];
    float4 w2 = Ws4[(k4 * 4 + 2) * 16 + cg];
    float4 w3 = Ws4[(k4 * 4 + 3) * 16 + cg];
    a0.x += xa.x * w0.x + xa.y * w1.x + xa.z * w2.x + xa.w * w3.x;
    a0.y += xa.x * w0.y + xa.y * w1.y + xa.z * w2.y + xa.w * w3.y;
    a0.z += xa.x * w0.z + xa.y * w1.z + xa.z * w2.z + xa.w * w3.z;
    a0.w += xa.x * w0.w + xa.y * w1.w + xa.z * w2.w + xa.w * w3.w;
    a1.x += xb.x * w0.x + xb.y * w1.x + xb.z * w2.x + xb.w * w3.x;
    a1.y += xb.x * w0.y + xb.y * w1.y + xb.z * w2.y + xb.w * w3.y;
    a1.z += xb.x * w0.z + xb.y * w1.z + xb.z * w2.z + xb.w * w3.z;
    a1.w += xb.x * w0.w + xb.y * w1.w + xb.z * w2.w + xb.w * w3.w;
  }
  if (base + r0 < N_) ((float4*)h1)[(size_t)(base + r0) * 16 + cg] = a0;
  if (base + r1 < N_) ((float4*)h1)[(size_t)(base + r1) * 16 + cg] = a1;
}

// ---------------- aggregation over 64-wide rows ----------------
// wave per node; 4 edge-groups x 16 lanes x float4; prefetched edge stream.
// MODE 1: += bias, relu (layer 1).  MODE 0: plain (layer 2, pre-GEMM).

template <int MODE>
__global__ __launch_bounds__(256) void k_agg64(const float* __restrict__ h,
                                               const float* __restrict__ dinv,
                                               const int* __restrict__ rowptr,
                                               const int* __restrict__ csr_src,
                                               const float* __restrict__ csr_nrm,
                                               const float* __restrict__ bias,
                                               float* __restrict__ out) {
  int wave = threadIdx.x >> 6, lane = threadIdx.x & 63;
  int i = blockIdx.x * 4 + wave;
  if (i >= N_) return;
  int g = lane >> 4, l = lane & 15;
  int e0 = rowptr[i], e1 = rowptr[i + 1];
  const float4* h4 = (const float4*)h;
  float4 acc{0, 0, 0, 0};
  int e = e0 + g;
  int src = -1; float nm = 0.f;
  if (e < e1) { src = csr_src[e]; nm = csr_nrm[e]; }
  int nit = (e1 - e0 + 3) >> 2;
  for (int it = 0; it < nit; ++it) {
    int en = e + 4;
    int srcn = -1; float nmn = 0.f;
    if (en < e1) { srcn = csr_src[en]; nmn = csr_nrm[en]; }   // prefetch next
    if (src >= 0) {
      float4 v = h4[(size_t)src * 16 + l];
      acc.x += nm * v.x; acc.y += nm * v.y;
      acc.z += nm * v.z; acc.w += nm * v.w;
    }
    e = en; src = srcn; nm = nmn;
  }
  // reduce across the 4 edge-groups
  #pragma unroll
  for (int off = 16; off < 64; off <<= 1) {
    acc.x += __shfl_xor(acc.x, off, 64);
    acc.y += __shfl_xor(acc.y, off, 64);
    acc.z += __shfl_xor(acc.z, off, 64);
    acc.w += __shfl_xor(acc.w, off, 64);
  }
  if (g == 0) {
    float di = dinv[i];
    float d2 = di * di;
    float4 v = h4[(size_t)i * 16 + l];     // self-loop
    acc.x += d2 * v.x; acc.y += d2 * v.y;
    acc.z += d2 * v.z; acc.w += d2 * v.w;
    if (MODE == 1) {
      float4 b = ((const float4*)bias)[l];
      acc.x = fmaxf(acc.x + b.x, 0.f);
      acc.y = fmaxf(acc.y + b.y, 0.f);
      acc.z = fmaxf(acc.z + b.z, 0.f);
      acc.w = fmaxf(acc.w + b.w, 0.f);
    }
    ((float4*)out)[(size_t)i * 16 + l] = acc;
  }
}

// ---------------- epilogue: out = normalize(hagg @ W2 + b2) ----------------

__global__ __launch_bounds__(256) void k_out(const float* __restrict__ hagg,
                                             const float* __restrict__ W2,
                                             const float* __restrict__ b2,
                                             float* __restrict__ out) {
  __shared__ float Ws[FH * FC];   // 10 KB, [k][c]
  int t = threadIdx.x;
  for (int i = t; i < FH * FC; i += 256) Ws[i] = W2[i];
  __syncthreads();
  int wave = t >> 6, lane = t & 63;
  int row = blockIdx.x * 4 + wave;
  if (row >= N_) return;
  float hv = hagg[(size_t)row * FH + lane];       // lane k holds h[row][k]
  float acc = (lane < FC) ? b2[lane] : 0.f;
  #pragma unroll
  for (int k = 0; k < FH; ++k) {
    float xk = __shfl(hv, k, 64);
    float wv = (lane < FC) ? Ws[k * FC + lane] : 0.f;
    acc += xk * wv;
  }
  float sq = (lane < FC) ? acc * acc : 0.f;
  #pragma unroll
  for (int off = 32; off > 0; off >>= 1) sq += __shfl_xor(sq, off, 64);
  float nrm = sqrtf(sq);
  if (lane < FC) out[(size_t)row * FC + lane] = acc / fmaxf(nrm, 1e-12f);
}

// ---------------- launch ----------------

extern "C" void kernel_launch(void* const* d_in, const int* in_sizes, int n_in,
                              void* d_out, int out_size, void* d_ws, size_t ws_size,
                              hipStream_t stream) {
  const float* x  = (const float*)d_in[0];
  const int*   ei = (const int*)d_in[1];
  const float* ew = (const float*)d_in[2];
  const float* W1 = (const float*)d_in[3];
  const float* b1 = (const float*)d_in[4];
  const float* W2 = (const float*)d_in[5];
  const float* b2 = (const float*)d_in[6];
  float* out = (float*)d_out;

  char* ws = (char*)d_ws;
  size_t off = 0;
  auto alloc = [&](size_t bytes) -> char* {
    char* p = ws + off;
    off = (off + bytes + 255) & ~(size_t)255;
    return p;
  };
  float* deg     = (float*)alloc((size_t)N_ * 4);      // becomes dinv after k_dinv
  int*   cnt     = (int*)  alloc((size_t)N_ * 4);
  int*   fill    = (int*)  alloc((size_t)N_ * 4);
  int*   partial = (int*)  alloc((size_t)N_ * 4);
  int*   bsums   = (int*)  alloc((size_t)(NB_SCAN + 1) * 4);
  int*   rowptr  = (int*)  alloc((size_t)(N_ + 1) * 4);
  int*   csr_src = (int*)  alloc((size_t)E_ * 4);
  float* csr_nrm = (float*)alloc((size_t)E_ * 4);
  float* h1      = (float*)alloc((size_t)N_ * FH * 4); // also reused as hagg
  float* h1r     = (float*)alloc((size_t)N_ * FH * 4);
  (void)ws_size; (void)in_sizes; (void)n_in; (void)out_size;

  k_init    <<<(N_ + 255) / 256, 256, 0, stream>>>(deg, cnt, fill);
  k_edge_deg<<<(E_ + 255) / 256, 256, 0, stream>>>(ei, ew, deg, cnt);
  k_dinv    <<<(N_ + 255) / 256, 256, 0, stream>>>(deg);
  k_scan1   <<<NB_SCAN,          256, 0, stream>>>(cnt, partial, bsums);
  k_scan2   <<<1,                512, 0, stream>>>(bsums);
  k_scan3   <<<(N_ + 1 + 255) / 256, 256, 0, stream>>>(partial, bsums, rowptr);
  k_fill    <<<(E_ + 255) / 256, 256, 0, stream>>>(ei, ew, deg, rowptr, fill, csr_src, csr_nrm);
  k_gemm1   <<<(N_ + G1_ROWS - 1) / G1_ROWS, 256, 0, stream>>>(x, W1, h1);
  k_agg64<1><<<(N_ + 3) / 4,     256, 0, stream>>>(h1, deg, rowptr, csr_src, csr_nrm, b1, h1r);
  k_agg64<0><<<(N_ + 3) / 4,     256, 0, stream>>>(h1r, deg, rowptr, csr_src, csr_nrm, nullptr, h1);
  k_out     <<<(N_ + 3) / 4,     256, 0, stream>>>(h1, W2, b2, out);
}

// Round 3
// 387.123 us; speedup vs baseline: 1.7482x; 1.3051x over previous
//
#include <hip/hip_runtime.h>

constexpr int N_ = 100000;
constexpr int E_ = 1600000;
constexpr int FIN = 128;
constexpr int FH  = 64;
constexpr int FC  = 40;
constexpr int NB_SCAN = (N_ + 255) / 256;   // 391
constexpr int G1_ROWS = 32;
constexpr float FIXS  = 8388608.0f;         // 2^23 fixed-point scale
constexpr float FIXSI = 1.0f / 8388608.0f;

// ---------------- degree+count via ONE packed u64 atomic ----------------
// high 32: edge count; low 32: fixed-point weight sum (max sum << 512, no carry).
// atomicAdd's returned old value gives each edge its rank within its dst bucket.

__global__ __launch_bounds__(256) void k_edge_deg(const int* __restrict__ ei,
                                                  const float* __restrict__ ew,
                                                  unsigned long long* __restrict__ packed,
                                                  int* __restrict__ rank) {
  int e = blockIdx.x * 256 + threadIdx.x;
  if (e >= E_) return;
  int d = ei[E_ + e];                 // dst = edge_index[1]
  unsigned int fx = (unsigned int)(ew[e] * FIXS + 0.5f);
  unsigned long long old =
      atomicAdd(&packed[d], (1ULL << 32) | (unsigned long long)fx);
  rank[e] = (int)(old >> 32);
}

__global__ __launch_bounds__(256) void k_dinv(const unsigned long long* __restrict__ packed,
                                              float* __restrict__ dinv,
                                              int* __restrict__ cnt) {
  int i = blockIdx.x * 256 + threadIdx.x;
  if (i < N_) {
    unsigned long long p = packed[i];
    float dg = 1.0f + (float)(unsigned int)(p & 0xffffffffu) * FIXSI;  // +self-loop
    dinv[i] = rsqrtf(dg);            // dg >= 1 always
    cnt[i] = (int)(p >> 32);
  }
}

// ---------------- exclusive scan (rowptr) ----------------

__global__ __launch_bounds__(256) void k_scan1(const int* __restrict__ cnt,
                                               int* __restrict__ partial,
                                               int* __restrict__ bsums) {
  __shared__ int s[256];
  int t = threadIdx.x, gid = blockIdx.x * 256 + t;
  int v = (gid < N_) ? cnt[gid] : 0;
  s[t] = v; __syncthreads();
  for (int off = 1; off < 256; off <<= 1) {
    int u = (t >= off) ? s[t - off] : 0;
    __syncthreads();
    s[t] += u; __syncthreads();
  }
  if (gid < N_) partial[gid] = s[t] - v;          // exclusive within block
  if (t == 255) bsums[blockIdx.x] = s[255];       // block total
}

__global__ __launch_bounds__(512) void k_scan2(int* bsums) {
  __shared__ int s[512];
  int t = threadIdx.x;
  int v = (t < NB_SCAN) ? bsums[t] : 0;
  s[t] = v; __syncthreads();
  for (int off = 1; off < 512; off <<= 1) {
    int u = (t >= off) ? s[t - off] : 0;
    __syncthreads();
    s[t] += u; __syncthreads();
  }
  if (t < NB_SCAN) bsums[t] = s[t] - v;           // exclusive
  if (t == 511) bsums[NB_SCAN] = s[511];          // grand total (== E_)
}

__global__ __launch_bounds__(256) void k_scan3(const int* __restrict__ partial,
                                               const int* __restrict__ bsums,
                                               int* __restrict__ rowptr) {
  int gid = blockIdx.x * 256 + threadIdx.x;
  if (gid < N_)       rowptr[gid] = partial[gid] + bsums[gid >> 8];
  else if (gid == N_) rowptr[N_]  = bsums[NB_SCAN];
}

// ---------------- CSR fill — atomic-free (uses precomputed rank) ----------------
// interleaved {src, norm} per edge: one 8B scattered write.

__global__ __launch_bounds__(256) void k_fill(const int* __restrict__ ei,
                                              const float* __restrict__ ew,
                                              const float* __restrict__ dinv,
                                              const int* __restrict__ rowptr,
                                              const int* __restrict__ rank,
                                              int2* __restrict__ csr) {
  int e = blockIdx.x * 256 + threadIdx.x;
  if (e >= E_) return;
  int s = ei[e], d = ei[E_ + e];
  float nm = dinv[s] * ew[e] * dinv[d];
  int pos = rowptr[d] + rank[e];
  csr[pos] = make_int2(s, __float_as_int(nm));
}

// ---------------- GEMM1: h1 = x @ W1  (128 -> 64) ----------------

__global__ __launch_bounds__(256) void k_gemm1(const float* __restrict__ x,
                                               const float* __restrict__ W1,
                                               float* __restrict__ h1) {
  __shared__ float4 Ws4[FIN * 16];      // [k][cg], 32 KB
  __shared__ float4 xs4[G1_ROWS * 32];  // [r][k4], 16 KB
  int t = threadIdx.x;
  const float4* W14 = (const float4*)W1;
  const float4* x4  = (const float4*)x;
  int base = blockIdx.x * G1_ROWS;
  #pragma unroll
  for (int i = 0; i < 8; ++i) Ws4[t + 256 * i] = W14[t + 256 * i];
  #pragma unroll
  for (int i = 0; i < 4; ++i) xs4[t + 256 * i] = x4[(size_t)base * 32 + t + 256 * i];
  __syncthreads();
  int cg = t & 15, rg = t >> 4;
  int r0 = rg * 2, r1 = r0 + 1;
  float4 a0{0, 0, 0, 0}, a1{0, 0, 0, 0};
  #pragma unroll 2
  for (int k4 = 0; k4 < 32; ++k4) {
    float4 xa = xs4[r0 * 32 + k4];
    float4 xb = xs4[r1 * 32 + k4];
    float4 w0 = Ws4[(k4 * 4 + 0) * 16 + cg];
    float4 w1 = Ws4[(k4 * 4 + 1) * 16 + cg];
    float4 w2 = Ws4[(k4 * 4 + 2) * 16 + cg];
    float4 w3 = Ws4[(k4 * 4 + 3) * 16 + cg];
    a0.x += xa.x * w0.x + xa.y * w1.x + xa.z * w2.x + xa.w * w3.x;
    a0.y += xa.x * w0.y + xa.y * w1.y + xa.z * w2.y + xa.w * w3.y;
    a0.z += xa.x * w0.z + xa.y * w1.z + xa.z * w2.z + xa.w * w3.z;
    a0.w += xa.x * w0.w + xa.y * w1.w + xa.z * w2.w + xa.w * w3.w;
    a1.x += xb.x * w0.x + xb.y * w1.x + xb.z * w2.x + xb.w * w3.x;
    a1.y += xb.x * w0.y + xb.y * w1.y + xb.z * w2.y + xb.w * w3.y;
    a1.z += xb.x * w0.z + xb.y * w1.z + xb.z * w2.z + xb.w * w3.z;
    a1.w += xb.x * w0.w + xb.y * w1.w + xb.z * w2.w + xb.w * w3.w;
  }
  if (base + r0 < N_) ((float4*)h1)[(size_t)(base + r0) * 16 + cg] = a0;
  if (base + r1 < N_) ((float4*)h1)[(size_t)(base + r1) * 16 + cg] = a1;
}

// ---------------- aggregation over 64-wide rows ----------------
// wave/node; 4 groups x 16 lanes x float4; TWO independent edge streams per
// group (stride 8) -> 8 gathers in flight per wave. MODE 1: +bias,relu.

template <int MODE>
__global__ __launch_bounds__(256) void k_agg64(const float* __restrict__ h,
                                               const float* __restrict__ dinv,
                                               const int* __restrict__ rowptr,
                                               const int2* __restrict__ csr,
                                               const float* __restrict__ bias,
                                               float* __restrict__ out) {
  int wave = threadIdx.x >> 6, lane = threadIdx.x & 63;
  int i = blockIdx.x * 4 + wave;
  if (i >= N_) return;
  int g = lane >> 4, l = lane & 15;
  int e0 = rowptr[i], e1 = rowptr[i + 1];
  const float4* h4 = (const float4*)h;
  float4 acc{0, 0, 0, 0};
  int eA = e0 + g, eB = eA + 4;
  int2 mA = make_int2(-1, 0), mB = make_int2(-1, 0);
  if (eA < e1) mA = csr[eA];
  if (eB < e1) mB = csr[eB];
  while (eA < e1) {
    int eA2 = eA + 8, eB2 = eB + 8;
    int2 nA = make_int2(-1, 0), nB = make_int2(-1, 0);
    if (eA2 < e1) nA = csr[eA2];
    if (eB2 < e1) nB = csr[eB2];
    float4 v = h4[(size_t)mA.x * 16 + l];
    float w = __int_as_float(mA.y);
    acc.x += w * v.x; acc.y += w * v.y; acc.z += w * v.z; acc.w += w * v.w;
    if (mB.x >= 0) {
      float4 u = h4[(size_t)mB.x * 16 + l];
      float wb = __int_as_float(mB.y);
      acc.x += wb * u.x; acc.y += wb * u.y; acc.z += wb * u.z; acc.w += wb * u.w;
    }
    eA = eA2; eB = eB2; mA = nA; mB = nB;
  }
  // reduce across the 4 edge-groups
  #pragma unroll
  for (int off = 16; off < 64; off <<= 1) {
    acc.x += __shfl_xor(acc.x, off, 64);
    acc.y += __shfl_xor(acc.y, off, 64);
    acc.z += __shfl_xor(acc.z, off, 64);
    acc.w += __shfl_xor(acc.w, off, 64);
  }
  if (g == 0) {
    float di = dinv[i];
    float d2 = di * di;
    float4 v = h4[(size_t)i * 16 + l];     // self-loop
    acc.x += d2 * v.x; acc.y += d2 * v.y;
    acc.z += d2 * v.z; acc.w += d2 * v.w;
    if (MODE == 1) {
      float4 b = ((const float4*)bias)[l];
      acc.x = fmaxf(acc.x + b.x, 0.f);
      acc.y = fmaxf(acc.y + b.y, 0.f);
      acc.z = fmaxf(acc.z + b.z, 0.f);
      acc.w = fmaxf(acc.w + b.w, 0.f);
    }
    ((float4*)out)[(size_t)i * 16 + l] = acc;
  }
}

// ---------------- epilogue: out = normalize(hagg @ W2 + b2) ----------------

__global__ __launch_bounds__(256) void k_out(const float* __restrict__ hagg,
                                             const float* __restrict__ W2,
                                             const float* __restrict__ b2,
                                             float* __restrict__ out) {
  __shared__ float Ws[FH * FC];   // 10 KB, [k][c]
  int t = threadIdx.x;
  for (int i = t; i < FH * FC; i += 256) Ws[i] = W2[i];
  __syncthreads();
  int wave = t >> 6, lane = t & 63;
  int row = blockIdx.x * 4 + wave;
  if (row >= N_) return;
  float hv = hagg[(size_t)row * FH + lane];       // lane k holds h[row][k]
  float acc = (lane < FC) ? b2[lane] : 0.f;
  #pragma unroll
  for (int k = 0; k < FH; ++k) {
    float xk = __shfl(hv, k, 64);
    float wv = (lane < FC) ? Ws[k * FC + lane] : 0.f;
    acc += xk * wv;
  }
  float sq = (lane < FC) ? acc * acc : 0.f;
  #pragma unroll
  for (int off = 32; off > 0; off >>= 1) sq += __shfl_xor(sq, off, 64);
  float nrm = sqrtf(sq);
  if (lane < FC) out[(size_t)row * FC + lane] = acc / fmaxf(nrm, 1e-12f);
}

// ---------------- launch ----------------

extern "C" void kernel_launch(void* const* d_in, const int* in_sizes, int n_in,
                              void* d_out, int out_size, void* d_ws, size_t ws_size,
                              hipStream_t stream) {
  const float* x  = (const float*)d_in[0];
  const int*   ei = (const int*)d_in[1];
  const float* ew = (const float*)d_in[2];
  const float* W1 = (const float*)d_in[3];
  const float* b1 = (const float*)d_in[4];
  const float* W2 = (const float*)d_in[5];
  const float* b2 = (const float*)d_in[6];
  float* out = (float*)d_out;

  char* ws = (char*)d_ws;
  size_t off = 0;
  auto alloc = [&](size_t bytes) -> char* {
    char* p = ws + off;
    off = (off + bytes + 255) & ~(size_t)255;
    return p;
  };
  unsigned long long* packed = (unsigned long long*)alloc((size_t)N_ * 8);
  float* dinv    = (float*)alloc((size_t)N_ * 4);
  int*   cnt     = (int*)  alloc((size_t)N_ * 4);
  int*   partial = (int*)  alloc((size_t)N_ * 4);
  int*   bsums   = (int*)  alloc((size_t)(NB_SCAN + 1) * 4);
  int*   rowptr  = (int*)  alloc((size_t)(N_ + 1) * 4);
  int*   rank    = (int*)  alloc((size_t)E_ * 4);
  int2*  csr     = (int2*) alloc((size_t)E_ * 8);
  float* h1      = (float*)alloc((size_t)N_ * FH * 4); // also reused as hagg
  float* h1r     = (float*)alloc((size_t)N_ * FH * 4);
  (void)ws_size; (void)in_sizes; (void)n_in; (void)out_size;

  hipMemsetAsync(packed, 0, (size_t)N_ * 8, stream);
  k_edge_deg<<<(E_ + 255) / 256, 256, 0, stream>>>(ei, ew, packed, rank);
  k_dinv    <<<(N_ + 255) / 256, 256, 0, stream>>>(packed, dinv, cnt);
  k_scan1   <<<NB_SCAN,          256, 0, stream>>>(cnt, partial, bsums);
  k_scan2   <<<1,                512, 0, stream>>>(bsums);
  k_scan3   <<<(N_ + 1 + 255) / 256, 256, 0, stream>>>(partial, bsums, rowptr);
  k_fill    <<<(E_ + 255) / 256, 256, 0, stream>>>(ei, ew, dinv, rowptr, rank, csr);
  k_gemm1   <<<(N_ + G1_ROWS - 1) / G1_ROWS, 256, 0, stream>>>(x, W1, h1);
  k_agg64<1><<<(N_ + 3) / 4,     256, 0, stream>>>(h1, dinv, rowptr, csr, b1, h1r);
  k_agg64<0><<<(N_ + 3) / 4,     256, 0, stream>>>(h1r, dinv, rowptr, csr, nullptr, h1);
  k_out     <<<(N_ + 3) / 4,     256, 0, stream>>>(h1, W2, b2, out);
}

// Round 4
// 321.161 us; speedup vs baseline: 2.1073x; 1.2054x over previous
//
#include <hip/hip_runtime.h>

constexpr int N_ = 100000;
constexpr int E_ = 1600000;
constexpr int FIN = 128;
constexpr int FH  = 64;
constexpr int FC  = 40;
constexpr int NB_SCAN = (N_ + 255) / 256;   // 391
constexpr int G1_ROWS = 32;
constexpr float FIXS  = 8388608.0f;         // 2^23 fixed-point scale
constexpr float FIXSI = 1.0f / 8388608.0f;

// ---------------- degree+count via ONE packed u64 atomic ----------------

__global__ __launch_bounds__(256) void k_edge_deg(const int* __restrict__ ei,
                                                  const float* __restrict__ ew,
                                                  unsigned long long* __restrict__ packed,
                                                  int* __restrict__ rank) {
  int e = blockIdx.x * 256 + threadIdx.x;
  if (e >= E_) return;
  int d = ei[E_ + e];                 // dst = edge_index[1]
  unsigned int fx = (unsigned int)(ew[e] * FIXS + 0.5f);
  unsigned long long old =
      atomicAdd(&packed[d], (1ULL << 32) | (unsigned long long)fx);
  rank[e] = (int)(old >> 32);
}

__global__ __launch_bounds__(256) void k_dinv(const unsigned long long* __restrict__ packed,
                                              float* __restrict__ dinv,
                                              int* __restrict__ cnt) {
  int i = blockIdx.x * 256 + threadIdx.x;
  if (i < N_) {
    unsigned long long p = packed[i];
    float dg = 1.0f + (float)(unsigned int)(p & 0xffffffffu) * FIXSI;  // +self-loop
    dinv[i] = rsqrtf(dg);            // dg >= 1 always
    cnt[i] = (int)(p >> 32);
  }
}

// ---------------- exclusive scan (rowptr) ----------------

__global__ __launch_bounds__(256) void k_scan1(const int* __restrict__ cnt,
                                               int* __restrict__ partial,
                                               int* __restrict__ bsums) {
  __shared__ int s[256];
  int t = threadIdx.x, gid = blockIdx.x * 256 + t;
  int v = (gid < N_) ? cnt[gid] : 0;
  s[t] = v; __syncthreads();
  for (int off = 1; off < 256; off <<= 1) {
    int u = (t >= off) ? s[t - off] : 0;
    __syncthreads();
    s[t] += u; __syncthreads();
  }
  if (gid < N_) partial[gid] = s[t] - v;          // exclusive within block
  if (t == 255) bsums[blockIdx.x] = s[255];       // block total
}

__global__ __launch_bounds__(512) void k_scan2(int* bsums) {
  __shared__ int s[512];
  int t = threadIdx.x;
  int v = (t < NB_SCAN) ? bsums[t] : 0;
  s[t] = v; __syncthreads();
  for (int off = 1; off < 512; off <<= 1) {
    int u = (t >= off) ? s[t - off] : 0;
    __syncthreads();
    s[t] += u; __syncthreads();
  }
  if (t < NB_SCAN) bsums[t] = s[t] - v;           // exclusive
  if (t == 511) bsums[NB_SCAN] = s[511];          // grand total (== E_)
}

__global__ __launch_bounds__(256) void k_scan3(const int* __restrict__ partial,
                                               const int* __restrict__ bsums,
                                               int* __restrict__ rowptr) {
  int gid = blockIdx.x * 256 + threadIdx.x;
  if (gid < N_)       rowptr[gid] = partial[gid] + bsums[gid >> 8];
  else if (gid == N_) rowptr[N_]  = bsums[NB_SCAN];
}

// ---------------- CSR fill — atomic-free (uses precomputed rank) ----------------

__global__ __launch_bounds__(256) void k_fill(const int* __restrict__ ei,
                                              const float* __restrict__ ew,
                                              const float* __restrict__ dinv,
                                              const int* __restrict__ rowptr,
                                              const int* __restrict__ rank,
                                              int2* __restrict__ csr) {
  int e = blockIdx.x * 256 + threadIdx.x;
  if (e >= E_) return;
  int s = ei[e], d = ei[E_ + e];
  float nm = dinv[s] * ew[e] * dinv[d];
  int pos = rowptr[d] + rank[e];
  csr[pos] = make_int2(s, __float_as_int(nm));
}

// ---------------- GEMM1: h1 = x @ W1  (128 -> 64) ----------------

__global__ __launch_bounds__(256) void k_gemm1(const float* __restrict__ x,
                                               const float* __restrict__ W1,
                                               float* __restrict__ h1) {
  __shared__ float4 Ws4[FIN * 16];      // [k][cg], 32 KB
  __shared__ float4 xs4[G1_ROWS * 32];  // [r][k4], 16 KB
  int t = threadIdx.x;
  const float4* W14 = (const float4*)W1;
  const float4* x4  = (const float4*)x;
  int base = blockIdx.x * G1_ROWS;
  #pragma unroll
  for (int i = 0; i < 8; ++i) Ws4[t + 256 * i] = W14[t + 256 * i];
  #pragma unroll
  for (int i = 0; i < 4; ++i) xs4[t + 256 * i] = x4[(size_t)base * 32 + t + 256 * i];
  __syncthreads();
  int cg = t & 15, rg = t >> 4;
  int r0 = rg * 2, r1 = r0 + 1;
  float4 a0{0, 0, 0, 0}, a1{0, 0, 0, 0};
  #pragma unroll 2
  for (int k4 = 0; k4 < 32; ++k4) {
    float4 xa = xs4[r0 * 32 + k4];
    float4 xb = xs4[r1 * 32 + k4];
    float4 w0 = Ws4[(k4 * 4 + 0) * 16 + cg];
    float4 w1 = Ws4[(k4 * 4 + 1) * 16 + cg];
    float4 w2 = Ws4[(k4 * 4 + 2) * 16 + cg];
    float4 w3 = Ws4[(k4 * 4 + 3) * 16 + cg];
    a0.x += xa.x * w0.x + xa.y * w1.x + xa.z * w2.x + xa.w * w3.x;
    a0.y += xa.x * w0.y + xa.y * w1.y + xa.z * w2.y + xa.w * w3.y;
    a0.z += xa.x * w0.z + xa.y * w1.z + xa.z * w2.z + xa.w * w3.z;
    a0.w += xa.x * w0.w + xa.y * w1.w + xa.z * w2.w + xa.w * w3.w;
    a1.x += xb.x * w0.x + xb.y * w1.x + xb.z * w2.x + xb.w * w3.x;
    a1.y += xb.x * w0.y + xb.y * w1.y + xb.z * w2.y + xb.w * w3.y;
    a1.z += xb.x * w0.z + xb.y * w1.z + xb.z * w2.z + xb.w * w3.z;
    a1.w += xb.x * w0.w + xb.y * w1.w + xb.z * w2.w + xb.w * w3.w;
  }
  if (base + r0 < N_) ((float4*)h1)[(size_t)(base + r0) * 16 + cg] = a0;
  if (base + r1 < N_) ((float4*)h1)[(size_t)(base + r1) * 16 + cg] = a1;
}

// ---------------- aggregation over 64-wide rows ----------------

template <int MODE>
__global__ __launch_bounds__(256) void k_agg64(const float* __restrict__ h,
                                               const float* __restrict__ dinv,
                                               const int* __restrict__ rowptr,
                                               const int2* __restrict__ csr,
                                               const float* __restrict__ bias,
                                               float* __restrict__ out) {
  int wave = threadIdx.x >> 6, lane = threadIdx.x & 63;
  int i = blockIdx.x * 4 + wave;
  if (i >= N_) return;
  int g = lane >> 4, l = lane & 15;
  int e0 = rowptr[i], e1 = rowptr[i + 1];
  const float4* h4 = (const float4*)h;
  float4 acc{0, 0, 0, 0};
  int eA = e0 + g, eB = eA + 4;
  int2 mA = make_int2(-1, 0), mB = make_int2(-1, 0);
  if (eA < e1) mA = csr[eA];
  if (eB < e1) mB = csr[eB];
  while (eA < e1) {
    int eA2 = eA + 8, eB2 = eB + 8;
    int2 nA = make_int2(-1, 0), nB = make_int2(-1, 0);
    if (eA2 < e1) nA = csr[eA2];
    if (eB2 < e1) nB = csr[eB2];
    float4 v = h4[(size_t)mA.x * 16 + l];
    float w = __int_as_float(mA.y);
    acc.x += w * v.x; acc.y += w * v.y; acc.z += w * v.z; acc.w += w * v.w;
    if (mB.x >= 0) {
      float4 u = h4[(size_t)mB.x * 16 + l];
      float wb = __int_as_float(mB.y);
      acc.x += wb * u.x; acc.y += wb * u.y; acc.z += wb * u.z; acc.w += wb * u.w;
    }
    eA = eA2; eB = eB2; mA = nA; mB = nB;
  }
  #pragma unroll
  for (int off = 16; off < 64; off <<= 1) {
    acc.x += __shfl_xor(acc.x, off, 64);
    acc.y += __shfl_xor(acc.y, off, 64);
    acc.z += __shfl_xor(acc.z, off, 64);
    acc.w += __shfl_xor(acc.w, off, 64);
  }
  if (g == 0) {
    float di = dinv[i];
    float d2 = di * di;
    float4 v = h4[(size_t)i * 16 + l];     // self-loop
    acc.x += d2 * v.x; acc.y += d2 * v.y;
    acc.z += d2 * v.z; acc.w += d2 * v.w;
    if (MODE == 1) {
      float4 b = ((const float4*)bias)[l];
      acc.x = fmaxf(acc.x + b.x, 0.f);
      acc.y = fmaxf(acc.y + b.y, 0.f);
      acc.z = fmaxf(acc.z + b.z, 0.f);
      acc.w = fmaxf(acc.w + b.w, 0.f);
    }
    ((float4*)out)[(size_t)i * 16 + l] = acc;
  }
}

// ---------------- epilogue: out = normalize(hagg @ W2 + b2) ----------------
// Block = 16 rows (4/wave). W2 transposed+padded in LDS; per-wave h rows in
// padded LDS. Lane (r, cg) computes cols {cg, cg+16, cg+32}; all 64 lanes live.

__global__ __launch_bounds__(256) void k_out(const float* __restrict__ hagg,
                                             const float* __restrict__ W2,
                                             const float* __restrict__ b2,
                                             float* __restrict__ out) {
  __shared__ float WsT[FC * 68];     // [c][k], ld=68 -> bank spread, 10.6 KB
  __shared__ float hs[4][4 * 68];    // per-wave: 4 rows, ld=68, 4.25 KB
  int t = threadIdx.x;
  for (int idx = t; idx < FC * FH; idx += 256) {
    int c = idx >> 6, k = idx & 63;
    WsT[c * 68 + k] = W2[k * FC + c];      // transpose into LDS (L1-hot)
  }
  __syncthreads();
  int wave = t >> 6, lane = t & 63;
  int r = lane >> 4, cg = lane & 15;
  int row = blockIdx.x * 16 + wave * 4 + r;   // 100000 = 6250*16: no tail
  // stage this wave's 4 rows (wave-local LDS: no barrier needed)
  const float4* h4 = (const float4*)hagg;
  float4* hs4 = (float4*)&hs[wave][0];
  hs4[r * 17 + cg] = h4[(size_t)row * 16 + cg];
  const float4* W4T = (const float4*)WsT;
  int c0 = cg, c1 = cg + 16, c2 = cg + 32;
  int c2r = (c2 < FC) ? c2 : 0;              // clamp; masked at epilogue
  float a0 = b2[c0], a1 = b2[c1], a2 = (c2 < FC) ? b2[c2] : 0.f;
  #pragma unroll
  for (int kl = 0; kl < 16; ++kl) {
    float4 hk = hs4[r * 17 + kl];            // broadcast within 16-lane group
    float4 w0 = W4T[c0 * 17 + kl];
    float4 w1 = W4T[c1 * 17 + kl];
    float4 w2 = W4T[c2r * 17 + kl];
    a0 += hk.x * w0.x + hk.y * w0.y + hk.z * w0.z + hk.w * w0.w;
    a1 += hk.x * w1.x + hk.y * w1.y + hk.z * w1.z + hk.w * w1.w;
    a2 += hk.x * w2.x + hk.y * w2.y + hk.z * w2.z + hk.w * w2.w;
  }
  float sq = a0 * a0 + a1 * a1 + ((c2 < FC) ? a2 * a2 : 0.f);
  #pragma unroll
  for (int off = 1; off < 16; off <<= 1) sq += __shfl_xor(sq, off, 64);
  float inv = 1.0f / fmaxf(sqrtf(sq), 1e-12f);
  float* orow = out + (size_t)row * FC;
  orow[c0] = a0 * inv;
  orow[c1] = a1 * inv;
  if (c2 < FC) orow[c2] = a2 * inv;
}

// ---------------- launch ----------------

extern "C" void kernel_launch(void* const* d_in, const int* in_sizes, int n_in,
                              void* d_out, int out_size, void* d_ws, size_t ws_size,
                              hipStream_t stream) {
  const float* x  = (const float*)d_in[0];
  const int*   ei = (const int*)d_in[1];
  const float* ew = (const float*)d_in[2];
  const float* W1 = (const float*)d_in[3];
  const float* b1 = (const float*)d_in[4];
  const float* W2 = (const float*)d_in[5];
  const float* b2 = (const float*)d_in[6];
  float* out = (float*)d_out;

  char* ws = (char*)d_ws;
  size_t off = 0;
  auto alloc = [&](size_t bytes) -> char* {
    char* p = ws + off;
    off = (off + bytes + 255) & ~(size_t)255;
    return p;
  };
  unsigned long long* packed = (unsigned long long*)alloc((size_t)N_ * 8);
  float* dinv    = (float*)alloc((size_t)N_ * 4);
  int*   cnt     = (int*)  alloc((size_t)N_ * 4);
  int*   partial = (int*)  alloc((size_t)N_ * 4);
  int*   bsums   = (int*)  alloc((size_t)(NB_SCAN + 1) * 4);
  int*   rowptr  = (int*)  alloc((size_t)(N_ + 1) * 4);
  int*   rank    = (int*)  alloc((size_t)E_ * 4);
  int2*  csr     = (int2*) alloc((size_t)E_ * 8);
  float* h1      = (float*)alloc((size_t)N_ * FH * 4); // also reused as hagg
  float* h1r     = (float*)alloc((size_t)N_ * FH * 4);
  (void)ws_size; (void)in_sizes; (void)n_in; (void)out_size;

  hipMemsetAsync(packed, 0, (size_t)N_ * 8, stream);
  k_edge_deg<<<(E_ + 255) / 256, 256, 0, stream>>>(ei, ew, packed, rank);
  k_dinv    <<<(N_ + 255) / 256, 256, 0, stream>>>(packed, dinv, cnt);
  k_scan1   <<<NB_SCAN,          256, 0, stream>>>(cnt, partial, bsums);
  k_scan2   <<<1,                512, 0, stream>>>(bsums);
  k_scan3   <<<(N_ + 1 + 255) / 256, 256, 0, stream>>>(partial, bsums, rowptr);
  k_fill    <<<(E_ + 255) / 256, 256, 0, stream>>>(ei, ew, dinv, rowptr, rank, csr);
  k_gemm1   <<<(N_ + G1_ROWS - 1) / G1_ROWS, 256, 0, stream>>>(x, W1, h1);
  k_agg64<1><<<(N_ + 3) / 4,     256, 0, stream>>>(h1, dinv, rowptr, csr, b1, h1r);
  k_agg64<0><<<(N_ + 3) / 4,     256, 0, stream>>>(h1r, dinv, rowptr, csr, nullptr, h1);
  k_out     <<<N_ / 16,          256, 0, stream>>>(h1, W2, b2, out);
}